// Round 3
// baseline (62.653 us; speedup 1.0000x reference)
//
#include <hip/hip_runtime.h>

// Grouped conv1d (kernel=3, pad=1) over last dim with circular input shift
// (+1 along axis 3) and circular output shift (+1 along axis 2).
// x: (128, 56, 56) fp32, W: (64, 16, 3) fp32, out: (32, 56, 56) fp32.
//
// y[o,k,n,m] = sum_{j} tp[p=m+j] * W[i,k,j] summed over i
// tp row (58 wide) = [0, x55, x0, x1, ..., x54, 0]
//
// LDS holds tp rows CONTIGUOUSLY (stride 60) so the 3 taps of thread m are
// xs[i*60 + m + {0,1,2}] -> compiler merges into ds_read2_b32 + ds_read_b32
// (128 LDS instrs/thread vs 192 with the verbatim layout).
// Staging stays branchless+vectorized: float4 global loads, written as two
// 8B-aligned ds_write_b64 at column +2; pad col 57 zeroed via cndmask; head
// pair (0, x55) via a 64-lane gather.

#define HDIM 56
#define WDIM 56
#define HW   (HDIM * WDIM)      // 3136
#define GI   64                 // input channels per group
#define KOUT 16                 // output channels per group
#define LPAD 60                 // LDS row stride (floats); 240 B -> rows 16B-aligned

__global__ __launch_bounds__(128) void shift_conv_kernel(
    const float* __restrict__ x, const float* __restrict__ Wg,
    float* __restrict__ out)
{
    __shared__ float xs[GI * LPAD];   // 64 x 60 x 4 B = 15 KB

    const int n  = blockIdx.x;   // input H row
    const int o  = blockIdx.y;   // channel group (0,1)
    const int kh = blockIdx.z;   // k half (0,1)

    const int tx  = threadIdx.x; // 0..63
    const int ty  = threadIdx.y; // 0..1
    const int tid = ty * 64 + tx;

    const float* xbase = x + (o * GI) * HW + n * WDIM;

    // head: xs[i][0..1] = {0, x[i][55]}  (64-lane gather, no conflicts w/ bulk)
    if (tid < GI) {
        float x55 = xbase[tid * HW + 55];
        *(float2*)(&xs[tid * LPAD]) = make_float2(0.0f, x55);
    }

    // bulk: src cols 4t..4t+3 -> LDS cols 4t+2..4t+5 (8B-aligned), 7 vec4/thread
    #pragma unroll
    for (int s = 0; s < 7; ++s) {
        int idx = tid + s * 128;          // 0..895
        int i   = idx / 14;               // row
        int t4  = idx - i * 14;           // float4 within row
        float4 v = *(const float4*)(xbase + i * HW + 4 * t4);
        if (t4 == 13) v.w = 0.0f;         // col 57 is pad, not x55
        float* d = &xs[i * LPAD + 4 * t4 + 2];
        *(float2*)(d)     = make_float2(v.x, v.y);
        *(float2*)(d + 2) = make_float2(v.z, v.w);
    }
    __syncthreads();

    // wave-uniform k0 (blockDim.x == 64 -> one ty per wave) => scalar W loads.
    // k0*12 bytes in {0,48,96,144}: 16B-aligned -> s_load_dwordx4 x3 per row
    int k0 = kh * 8 + ty * 4;
    k0 = __builtin_amdgcn_readfirstlane(k0);

    const int m = (tx < WDIM) ? tx : (WDIM - 1);   // clamp idle lanes

    float acc0 = 0.f, acc1 = 0.f, acc2 = 0.f, acc3 = 0.f;
    const float* wk = Wg + k0 * 3;   // 12 contiguous floats per i

    #pragma unroll 8
    for (int i = 0; i < GI; ++i) {
        const float* r = &xs[i * LPAD + m];   // taps contiguous -> ds_read2
        float a0 = r[0];
        float a1 = r[1];
        float a2 = r[2];
        const float* w = wk + i * (KOUT * 3);
        acc0 = fmaf(a2, w[2],  fmaf(a1, w[1],  fmaf(a0, w[0],  acc0)));
        acc1 = fmaf(a2, w[5],  fmaf(a1, w[4],  fmaf(a0, w[3],  acc1)));
        acc2 = fmaf(a2, w[8],  fmaf(a1, w[7],  fmaf(a0, w[6],  acc2)));
        acc3 = fmaf(a2, w[11], fmaf(a1, w[10], fmaf(a0, w[9],  acc3)));
    }

    if (tx < WDIM) {
        const int n1 = (n == HDIM - 1) ? 0 : (n + 1);  // output roll along H
        float* ob = out + ((o * KOUT + k0) * HDIM + n1) * WDIM + tx;
        ob[0]      = acc0;
        ob[HW]     = acc1;
        ob[2 * HW] = acc2;
        ob[3 * HW] = acc3;
    }
}

extern "C" void kernel_launch(void* const* d_in, const int* in_sizes, int n_in,
                              void* d_out, int out_size, void* d_ws, size_t ws_size,
                              hipStream_t stream) {
    const float* x  = (const float*)d_in[0];   // 128*56*56
    const float* Wg = (const float*)d_in[1];   // 64*16*3
    float* out      = (float*)d_out;           // 32*56*56

    dim3 grid(HDIM, 2, 2);   // (n, o, k-half) = 224 blocks
    dim3 block(64, 2, 1);    // 2 waves
    hipLaunchKernelGGL(shift_conv_kernel, grid, block, 0, stream, x, Wg, out);
}